// Round 8
// baseline (107.827 us; speedup 1.0000x reference)
//
#include <hip/hip_runtime.h>
#include <math.h>

#define RPOOL 5

// Kernel byte-identical to R6 (known correct, 30.5 us as a single launch).
__global__ __launch_bounds__(256, 4)
void minmax_pool_sort_kernel(const float* __restrict__ x,
                             const int* __restrict__ lengths,
                             float* __restrict__ out,
                             int n, int L) {
    const int lane = threadIdx.x & 63;
    const int row = __builtin_amdgcn_readfirstlane(blockIdx.x * 4 + (threadIdx.x >> 6));
    if (row >= n) return;

    const int l = __builtin_amdgcn_readfirstlane(lengths[row]);
    const float* xr = x + (long long)row * L;

    int s[RPOOL], e[RPOOL];
#pragma unroll
    for (int j = 0; j < RPOOL; ++j) {
        s[j] = (j * l) / RPOOL;                      // floor(j*l/R)
        e[j] = ((j + 1) * l + RPOOL - 1) / RPOOL;    // ceil((j+1)*l/R)
    }

    float4 v[RPOOL];
    int    t0[RPOOL];
#pragma unroll
    for (int j = 0; j < RPOOL; ++j) {
        const int sa = s[j] & ~3;            // 16B-aligned start
        const int t  = sa + lane * 4;
        t0[j] = t;
        const int idx = (t < e[j]) ? t : 0;  // clamp OOB lanes into the row
        v[j] = *reinterpret_cast<const float4*>(xr + idx);
    }

    float mx[RPOOL], mn[RPOOL];
#pragma unroll
    for (int j = 0; j < RPOOL; ++j) {
        const float vv0 = v[j].x, vv1 = v[j].y, vv2 = v[j].z, vv3 = v[j].w;
        const int t = t0[j];
        const bool ok0 = (t     >= s[j]) & (t     < e[j]);
        const bool ok1 = (t + 1 >= s[j]) & (t + 1 < e[j]);
        const bool ok2 = (t + 2 >= s[j]) & (t + 2 < e[j]);
        const bool ok3 = (t + 3 >= s[j]) & (t + 3 < e[j]);
        const float m0 = ok0 ? vv0 : -INFINITY, n0 = ok0 ? vv0 : INFINITY;
        const float m1 = ok1 ? vv1 : -INFINITY, n1 = ok1 ? vv1 : INFINITY;
        const float m2 = ok2 ? vv2 : -INFINITY, n2 = ok2 ? vv2 : INFINITY;
        const float m3 = ok3 ? vv3 : -INFINITY, n3 = ok3 ? vv3 : INFINITY;
        mx[j] = fmaxf(fmaxf(m0, m1), fmaxf(m2, m3));
        mn[j] = fminf(fminf(n0, n1), fminf(n2, n3));
    }

#pragma unroll
    for (int off = 32; off > 0; off >>= 1) {
#pragma unroll
        for (int j = 0; j < RPOOL; ++j) {
            mx[j] = fmaxf(mx[j], __shfl_xor(mx[j], off, 64));
            mn[j] = fminf(mn[j], __shfl_xor(mn[j], off, 64));
        }
    }

    float vals[2 * RPOOL];
#pragma unroll
    for (int j = 0; j < RPOOL; ++j) { vals[j] = mx[j]; vals[RPOOL + j] = mn[j]; }

#pragma unroll
    for (int i = 0; i < 2 * RPOOL - 1; ++i) {
#pragma unroll
        for (int k = 0; k < 2 * RPOOL - 1 - i; ++k) {
            const float a = vals[k];
            const float b = vals[k + 1];
            vals[k]     = fminf(a, b);
            vals[k + 1] = fmaxf(a, b);
        }
    }

    float ov = vals[0];
#pragma unroll
    for (int k = 1; k < 2 * RPOOL; ++k) ov = (lane == k) ? vals[k] : ov;
    if (lane < 2 * RPOOL) out[(long long)row * (2 * RPOOL) + lane] = ov;
}

extern "C" void kernel_launch(void* const* d_in, const int* in_sizes, int n_in,
                              void* d_out, int out_size, void* d_ws, size_t ws_size,
                              hipStream_t stream) {
    const float* x       = (const float*)d_in[0];
    const int*   lengths = (const int*)d_in[1];
    float*       out     = (float*)d_out;

    const int n = in_sizes[1];            // N rows
    const int L = in_sizes[0] / n;        // row stride (1000)

    const int blocks = (n + 3) / 4;       // 4 waves (rows) per 256-thread block

    // CALIBRATION: 4 identical, idempotent launches. dur = overhead + 4*T_k
    // (vs R6's overhead + T_k = 30.5 us) separates fixed per-replay overhead
    // from true kernel GPU time. Deterministic: same output rewritten 4x.
    for (int rep = 0; rep < 4; ++rep) {
        hipLaunchKernelGGL(minmax_pool_sort_kernel, dim3(blocks), dim3(256), 0, stream,
                           x, lengths, out, n, L);
    }
}